// Round 3
// baseline (108.828 us; speedup 1.0000x reference)
//
#include <hip/hip_runtime.h>
#include <math.h>

#define BB 4
#define NQ 512
#define NK 1024
#define DH 64

// =================== MLP: W resident in VGPRs, 4 rows/wave ===================
// 256-thread blocks, 16 rows/block. Layer 1: lane = hidden dim, x via wave-
// uniform s_loads. Layer 2: broadcast h across lanes with v_readlane (VALU,
// no LDS). Writes TRANSPOSED kT[b][d][j] / qT[b][d][i] for the attn kernel.
#define MROWS 16

__global__ __launch_bounds__(256, 2) void mlp_kernel(
    const float* __restrict__ x1, const float* __restrict__ x2,
    const float* __restrict__ Wk1, const float* __restrict__ bk1,
    const float* __restrict__ Wk2, const float* __restrict__ bk2,
    const float* __restrict__ Wq1, const float* __restrict__ bq1,
    const float* __restrict__ Wq2, const float* __restrict__ bq2,
    float* __restrict__ kT, float* __restrict__ qT)
{
    const int t    = threadIdx.x;
    const int lane = t & 63;
    const int wav  = __builtin_amdgcn_readfirstlane(t >> 6);

    const int  NKBLK = (BB * NK) / MROWS;            // 256 key-path blocks
    const bool isk   = (int)blockIdx.x < NKBLK;
    const int  rblk  = isk ? (int)blockIdx.x : (int)blockIdx.x - NKBLK;

    const float* __restrict__ xb = isk ? x1 : x2;
    const float* __restrict__ W1 = isk ? Wk1 : Wq1;
    const float* __restrict__ b1 = isk ? bk1 : bq1;
    const float* __restrict__ W2 = isk ? Wk2 : Wq2;
    const float* __restrict__ b2 = isk ? bk2 : bq2;
    float* __restrict__ oT = isk ? kT : qT;
    const int seq = isk ? NK : NQ;
    const int lgs = isk ? 10 : 9;

    // W columns for this lane: 128 VGPRs, loaded once per block
    float w1r[DH], w2r[DH];
    #pragma unroll
    for (int d = 0; d < DH; ++d) {
        w1r[d] = W1[d * DH + lane];
        w2r[d] = W2[d * DH + lane];
    }
    const float b1v = b1[lane];
    const float b2v = b2[lane];

    const int row0 = rblk * MROWS + wav * 4;
    #pragma unroll
    for (int rr = 0; rr < 4; ++rr) {
        const int row = row0 + rr;                   // row within k or q region
        const float* xr = xb + (size_t)row * DH;     // wave-uniform -> s_load
        float acc = b1v;
        #pragma unroll
        for (int d = 0; d < DH; ++d) acc = fmaf(xr[d], w1r[d], acc);
        const float h = fmaxf(acc, 0.0f);            // relu (layer 1 only)
        float acc2 = b2v;
        #pragma unroll
        for (int d = 0; d < DH; ++d) {
            const float hd = __int_as_float(
                __builtin_amdgcn_readlane(__float_as_int(h), d));
            acc2 = fmaf(hd, w2r[d], acc2);
        }
        const int bidx = row >> lgs;
        const int sidx = row & (seq - 1);
        oT[((size_t)bidx * DH + lane) * seq + sidx] = acc2;   // transposed scatter
    }
}

// =================== Laplace attention, two-pass softmax ===================
// 256-thread blocks (4 waves), TQ=4 queries/block, grid = 512 -> 2 blocks/CU.
// Score: wave w owns keys [w*256, w*256+256), lane = 4 keys (float4 kT loads,
// coalesced); q via wave-uniform s_loads. Softmax stats in-wave + tiny LDS.
// PV: lane = d, p broadcast from LDS via b128, r coalesced dword loads.
#define TQ 4
#define NWAVE 4
#define KPW (NK / NWAVE)   // 256 keys per wave

__global__ __launch_bounds__(256, 2) void attn_kernel(
    const float* __restrict__ kT, const float* __restrict__ qT,
    const float* __restrict__ rmat, float* __restrict__ outp)
{
    __shared__ float p_s[TQ * NK];            // 16 KB weights; reused for partials
    __shared__ float wmin_s[NWAVE * TQ];
    __shared__ float wsum_s[NWAVE * TQ];

    const int t    = threadIdx.x;
    const int lane = t & 63;
    const int wav  = __builtin_amdgcn_readfirstlane(t >> 6);

    const int b  = blockIdx.x / (NQ / TQ);
    const int i0 = (blockIdx.x % (NQ / TQ)) * TQ;

    const float* kTb = kT + (size_t)b * DH * NK;
    const float* qTb = qT + (size_t)b * DH * NQ;

    const int j0 = wav * KPW + 4 * lane;      // this lane's four keys

    // ---- score phase ----
    float s[TQ][4];
    #pragma unroll
    for (int i = 0; i < TQ; ++i)
        { s[i][0] = 0.f; s[i][1] = 0.f; s[i][2] = 0.f; s[i][3] = 0.f; }

    #pragma unroll 8
    for (int d = 0; d < DH; ++d) {
        const float4 kv = *(const float4*)&kTb[d * NK + j0];   // coalesced 1KB/wave
        const float* qrow = qTb + d * NQ + i0;                 // uniform -> s_load
        #pragma unroll
        for (int i = 0; i < TQ; ++i) {
            const float q = qrow[i];
            s[i][0] += fabsf(kv.x - q);
            s[i][1] += fabsf(kv.y - q);
            s[i][2] += fabsf(kv.z - q);
            s[i][3] += fabsf(kv.w - q);
        }
    }

    // ---- softmax pass 1: global min of s per query ----
    #pragma unroll
    for (int i = 0; i < TQ; ++i) {
        float m = fminf(fminf(s[i][0], s[i][1]), fminf(s[i][2], s[i][3]));
        #pragma unroll
        for (int off = 32; off > 0; off >>= 1)
            m = fminf(m, __shfl_xor(m, off, 64));
        if (lane == 0) wmin_s[wav * TQ + i] = m;
    }
    __syncthreads();

    float M[TQ];
    #pragma unroll
    for (int i = 0; i < TQ; ++i) {
        float m = wmin_s[i];
        #pragma unroll
        for (int g = 1; g < NWAVE; ++g) m = fminf(m, wmin_s[g * TQ + i]);
        M[i] = m;
    }

    // ---- softmax pass 2: p = exp(M - s), per-query sums, stage p to LDS ----
    #pragma unroll
    for (int i = 0; i < TQ; ++i) {
        float4 p4;
        p4.x = __expf(M[i] - s[i][0]);
        p4.y = __expf(M[i] - s[i][1]);
        p4.z = __expf(M[i] - s[i][2]);
        p4.w = __expf(M[i] - s[i][3]);
        *(float4*)&p_s[i * NK + j0] = p4;
        float cs = (p4.x + p4.y) + (p4.z + p4.w);
        #pragma unroll
        for (int off = 32; off > 0; off >>= 1)
            cs += __shfl_xor(cs, off, 64);
        if (lane == 0) wsum_s[wav * TQ + i] = cs;
    }
    __syncthreads();

    // ---- PV: lane = d, wave w covers keys [w*KPW, w*KPW+KPW) ----
    float O[TQ];
    #pragma unroll
    for (int i = 0; i < TQ; ++i) O[i] = 0.0f;

    const float* rb = rmat + ((size_t)b * NK + wav * KPW) * DH;
    for (int kk = 0; kk < KPW; kk += 4) {
        const float rv0 = rb[(kk + 0) * DH + lane];            // coalesced 256B
        const float rv1 = rb[(kk + 1) * DH + lane];
        const float rv2 = rb[(kk + 2) * DH + lane];
        const float rv3 = rb[(kk + 3) * DH + lane];
        #pragma unroll
        for (int i = 0; i < TQ; ++i) {
            const float4 p4 = *(const float4*)&p_s[i * NK + wav * KPW + kk];
            O[i] = fmaf(p4.x, rv0, O[i]);
            O[i] = fmaf(p4.y, rv1, O[i]);
            O[i] = fmaf(p4.z, rv2, O[i]);
            O[i] = fmaf(p4.w, rv3, O[i]);
        }
    }
    __syncthreads();   // all waves done reading p_s

    // ---- cross-wave combine (reuse p_s region) ----
    float* part = p_s;  // needs NWAVE*TQ*64 = 1024 floats
    #pragma unroll
    for (int i = 0; i < TQ; ++i)
        part[(wav * TQ + i) * 64 + lane] = O[i];
    __syncthreads();

    const int q = wav;  // TQ == NWAVE: wave w finalizes query i0+w
    float sum = 0.0f;
    #pragma unroll
    for (int g = 0; g < NWAVE; ++g)
        sum += part[(g * TQ + q) * 64 + lane];
    float l = 0.0f;
    #pragma unroll
    for (int g = 0; g < NWAVE; ++g)
        l += wsum_s[g * TQ + q];
    outp[((size_t)b * NQ + i0 + q) * DH + lane] = sum / l;
}

extern "C" void kernel_launch(void* const* d_in, const int* in_sizes, int n_in,
                              void* d_out, int out_size, void* d_ws, size_t ws_size,
                              hipStream_t stream) {
    const float* x1  = (const float*)d_in[0];
    const float* x2  = (const float*)d_in[1];
    const float* r   = (const float*)d_in[2];
    const float* Wk1 = (const float*)d_in[3];
    const float* bk1 = (const float*)d_in[4];
    const float* Wk2 = (const float*)d_in[5];
    const float* bk2 = (const float*)d_in[6];
    const float* Wq1 = (const float*)d_in[7];
    const float* bq1 = (const float*)d_in[8];
    const float* Wq2 = (const float*)d_in[9];
    const float* bq2 = (const float*)d_in[10];
    float* out = (float*)d_out;

    float* kT = (float*)d_ws;                     // B*DH*NK floats (transposed keys)
    float* qT = kT + (size_t)BB * DH * NK;        // B*DH*NQ floats (transposed queries)

    mlp_kernel<<<(BB * (NK + NQ)) / MROWS, 256, 0, stream>>>(
        x1, x2, Wk1, bk1, Wk2, bk2, Wq1, bq1, Wq2, bq2, kT, qT);

    attn_kernel<<<BB * (NQ / TQ), 256, 0, stream>>>(kT, qT, r, out);
}